// Round 3
// baseline (2415.618 us; speedup 1.0000x reference)
//
#include <hip/hip_runtime.h>
#include <stdint.h>

// Problem constants (DecoderLSTM): VOCAB=50257, E=H=512, B=32, S=512
// ALL float tensors are fp32; sequence is int32. Internal bf16 MFMA; fp32 out.
#define EDIM  512
#define HDIM  512
#define BSZ   32
#define SLEN  512
#define GDIM  2048   // 4*H
#define GWG   32     // number of scan workgroups (h-column split)

// Sentinel for unwritten hist u64s: 4x bf16 0xFFFF (-NaN). h = o*tanh(c) is in
// [-1,1]; f2bf of any finite in-range value can never produce 0xFFFF, and the
// u64 store is atomic (no tearing), so "u64 != SENT" == "data ready".
#define SENT 0xFFFFFFFFFFFFFFFFull

typedef __bf16 bf16x8 __attribute__((ext_vector_type(8)));
typedef float  f32x4  __attribute__((ext_vector_type(4)));

__device__ __forceinline__ uint16_t f2bf(float f) {
  union { float f; uint32_t i; } v; v.f = f;
  uint32_t r = v.i + 0x7FFFu + ((v.i >> 16) & 1u);  // RNE
  return (uint16_t)(r >> 16);
}
__device__ __forceinline__ float bf2f(uint32_t u) {
  union { uint32_t i; float f; } v; v.i = u << 16; return v.f;
}
union BF8 { uint16_t u[8]; uint4 v; bf16x8 b; unsigned long long q[2]; };
union BF4 { uint16_t u[4]; unsigned long long q; };
__device__ __forceinline__ uint4 pack8(float4 lo, float4 hi) {
  BF8 r;
  r.u[0] = f2bf(lo.x); r.u[1] = f2bf(lo.y); r.u[2] = f2bf(lo.z); r.u[3] = f2bf(lo.w);
  r.u[4] = f2bf(hi.x); r.u[5] = f2bf(hi.y); r.u[6] = f2bf(hi.z); r.u[7] = f2bf(hi.w);
  return r.v;
}
__device__ __forceinline__ float sigm(float x) { return 1.0f / (1.0f + __expf(-x)); }
__device__ __forceinline__ float tanh_(float x) {
  float ax = fabsf(x);
  float e  = __expf(2.0f * ax);          // overflow-safe: e=inf -> t=1
  float t  = 1.0f - 2.0f / (e + 1.0f);
  return copysignf(t, x);
}
__device__ __forceinline__ unsigned allc32(const unsigned* p) {
  return __hip_atomic_load(p, __ATOMIC_RELAXED, __HIP_MEMORY_SCOPE_AGENT);
}
// Atomic (LLC, L1/L2-bypassing) u64 load — used ONLY for straggler re-polls.
__device__ __forceinline__ unsigned long long allc64(const unsigned long long* p) {
  return __hip_atomic_load(p, __ATOMIC_RELAXED, __HIP_MEMORY_SCOPE_AGENT);
}

// ---------------------------------------------------------------------------
// K1: const[g][b] = sum_k W_hh[g][k]*h0[b][k] + b_ih[g] + b_hh[g] (fp32);
// also zeroes the 64 per-(half,wg) flag words (512 u32 region).
// ---------------------------------------------------------------------------
__global__ __launch_bounds__(256) void k_const(
    const float* __restrict__ Whh, const float* __restrict__ h0,
    const float* __restrict__ bih, const float* __restrict__ bhh,
    float* __restrict__ cgb, unsigned* __restrict__ flags)
{
  int idx = blockIdx.x * 256 + threadIdx.x;        // 2048*32 = 65536
  if (idx < 512) flags[idx] = 0u;                  // 64 lines @ 32B stride
  int g = idx >> 5, b = idx & 31;
  const float4* w4 = (const float4*)(Whh + (size_t)g * HDIM);
  const float4* h4 = (const float4*)(h0  + (size_t)b * HDIM);
  float acc = 0.f;
  #pragma unroll 8
  for (int k = 0; k < HDIM / 4; k++) {
    float4 a = w4[k], c = h4[k];
    acc += a.x * c.x + a.y * c.y + a.z * c.z + a.w * c.w;
  }
  acc += bih[g] + bhh[g];
  cgb[idx] = acc;   // layout [g][b]
}

// ---------------------------------------------------------------------------
// K2: eg[s][b][g] (bf16) = sum_e emb[seq[b][s]][e] * W_ih[g][e] + const[g][b]
// (unchanged)
// ---------------------------------------------------------------------------
__global__ __launch_bounds__(256) void k_emb(
    const int* __restrict__ seq, const float* __restrict__ emb,
    const float* __restrict__ Wih, const float* __restrict__ cgb,
    uint16_t* __restrict__ eg)
{
  __shared__ uint4 wlds[4096];   // 64KB bf16, frag-order: [T=n>>4][kc][nl=n&15][q]
  const int tid = threadIdx.x;
  const int gc  = blockIdx.x & 31;   // 32 g-chunks of 64 rows
  const int sc  = blockIdx.x >> 5;   // 128 s-chunks of 4
  const int g0  = gc * 64, s0 = sc * 4;

  for (int i = tid; i < 64 * 64; i += 256) {       // 64 rows x 64 8-elem chunks
    int n = i >> 6, c = i & 63;
    const float* wp = Wih + (size_t)(g0 + n) * 1024 + c * 8;   // W_e = W_ih[:, :512]
    float4 lo = *(const float4*)(wp);
    float4 hi = *(const float4*)(wp + 4);
    wlds[(((n >> 4) * 16 + (c >> 2)) << 6) + ((n & 15) << 2) + (c & 3)] = pack8(lo, hi);
  }
  __syncthreads();

  const int lane = tid & 63, w = tid >> 6;
  const int q = lane >> 4, nl = lane & 15;
  const int Nt  = w & 1;            // b-tile
  const int Mt0 = (w >> 1) * 2;     // g-tile pair {Mt0, Mt0+1}
  const int bcol = Nt * 16 + nl;

  float c0i[4], c1i[4];             // baked const, fixed across s
  #pragma unroll
  for (int r = 0; r < 4; r++) {
    c0i[r] = cgb[(g0 + (Mt0    ) * 16 + q * 4 + r) * 32 + bcol];
    c1i[r] = cgb[(g0 + (Mt0 + 1) * 16 + q * 4 + r) * 32 + bcol];
  }

  for (int si = 0; si < 4; si++) {
    int s = s0 + si;
    int rowi = seq[bcol * SLEN + s];                 // gather index for this lane's b
    const float* brow = emb + (size_t)rowi * EDIM + q * 8;
    f32x4 acc0, acc1;
    #pragma unroll
    for (int r = 0; r < 4; r++) { acc0[r] = c0i[r]; acc1[r] = c1i[r]; }
    #pragma unroll 4
    for (int kc = 0; kc < 16; kc++) {
      float4 blo = *(const float4*)(brow + kc * 32);
      float4 bhi = *(const float4*)(brow + kc * 32 + 4);
      BF8 bf; bf.v = pack8(blo, bhi);
      BF8 a0; a0.v = wlds[(((Mt0    ) * 16 + kc) << 6) + (nl << 2) + q];
      BF8 a1; a1.v = wlds[(((Mt0 + 1) * 16 + kc) << 6) + (nl << 2) + q];
      acc0 = __builtin_amdgcn_mfma_f32_16x16x32_bf16(a0.b, bf.b, acc0, 0, 0, 0);
      acc1 = __builtin_amdgcn_mfma_f32_16x16x32_bf16(a1.b, bf.b, acc1, 0, 0, 0);
    }
    #pragma unroll
    for (int r = 0; r < 4; r++) {
      int m0 = (Mt0    ) * 16 + q * 4 + r;
      int m1 = (Mt0 + 1) * 16 + q * 4 + r;
      eg[((size_t)s * 32 + bcol) * GDIM + g0 + m0] = f2bf(acc0[r]);   // [s][b][g]
      eg[((size_t)s * 32 + bcol) * GDIM + g0 + m1] = f2bf(acc1[r]);
    }
  }
}

// ---------------------------------------------------------------------------
// K3: sequential scan — R10: per-wave flag stores (no RMW) + sticky poll
// cache + eg one-step prefetch. Post-mortem R9 (1812us, down from 2500):
// protocol works; remaining ~8.5k cy/step is suspected to be (a) the 32-way
// same-line atomicAdd serialization at the LLC (the LAST producer's RMW —
// the one that gates detection — queues behind up to 31 others, every step),
// and (b) the eg stream missing LLC to HBM (~900cy) issued in the same step
// that consumes it.
// R10 changes, everything else identical to R9:
//  * signal: producer wave stores flag[(half,wg)] = t+1 (monotonic, atomic
//    STORE not RMW, fire-and-forget, no drain). Consumer wave: 32 lanes poll
//    32 flag words in parallel; a lane that has seen >= t caches the value
//    and skips re-loading (flags are monotonic) -> steady-state polls only
//    touch stragglers.
//  * eg[t+1] is prefetched at the top of step t; its HBM-miss latency
//    overlaps the whole step instead of sitting on the step-t critical path.
// Correctness still rests entirely on the data sentinel (write-once slots,
// atomic u64 stores, unreachable poison pattern); flags remain a throttle.
// ---------------------------------------------------------------------------
__global__ __launch_bounds__(128) void k_scan(
    const float* __restrict__ Wih, const float* __restrict__ c0,
    const uint16_t* __restrict__ eg, unsigned long long* __restrict__ hist,
    float* __restrict__ out, unsigned* __restrict__ flags)
{
  __shared__ uint4 wlds[4096];   // 64KB
  const int tid = threadIdx.x;
  const int wg  = blockIdx.x;
  const int j0  = wg * 16;

  // Stage W_h slice: row n: gate=n>>4, jj=n&15 -> W_ih row gate*512+j0+jj, cols [512,1024)
  for (int i = tid; i < 64 * 64; i += 128) {
    int n = i >> 6, c = i & 63;
    int grow = (n >> 4) * HDIM + j0 + (n & 15);
    const float* wp = Wih + (size_t)grow * 1024 + 512 + c * 8;
    float4 lo = *(const float4*)(wp);
    float4 hi = *(const float4*)(wp + 4);
    wlds[(((n >> 4) * 16 + (c >> 2)) << 6) + ((n & 15) << 2) + (c & 3)] = pack8(lo, hi);
  }

  const int lane = tid & 63, w = tid >> 6;   // w = batch half (N-tile)
  const int q = lane >> 4, nl = lane & 15;
  const int b  = w * 16 + nl;                // owned batch (C col)
  const int jq = j0 + q * 4;                 // owned j's: jq..jq+3 (C rows)
  const int jblk = wg * 4 + q;               // owned j-block (u64 of 4 bf16)
  // Flag words: index (half*32 + wg), stride 8 u32 (32B). Producer line:
  unsigned* myflag = flags + (size_t)(w * 32 + wg) * 8;
  // Consumer poll target for lane l<32: flags[(w*32 + l)*8]
  const unsigned* pollp = flags + (size_t)(w * 32 + (lane & 31)) * 8;
  unsigned fcache = 0u;                      // sticky cached flag (monotonic)
  float c0r[4];
  #pragma unroll
  for (int r = 0; r < 4; r++) c0r[r] = c0[(size_t)b * HDIM + jq + r];
  __syncthreads();   // LDS W_h ready — the ONLY barrier in this kernel

  // Preload eg for t=0
  ushort4 egv[4], egp[4];
  #pragma unroll
  for (int nt = 0; nt < 4; nt++)
    egv[nt] = *(const ushort4*)(eg + ((size_t)0 * 32 + b) * GDIM + nt * HDIM + jq);

  for (int t = 0; t < SLEN; t++) {
    // Prefetch eg[t+1]: in flight across the entire step (HBM miss hidden)
    const int tn = (t + 1 < SLEN) ? t + 1 : t;
    #pragma unroll
    for (int nt = 0; nt < 4; nt++)
      egp[nt] = *(const ushort4*)(eg + ((size_t)tn * 32 + b) * GDIM + nt * HDIM + jq);

    f32x4 acc[4];
    #pragma unroll
    for (int nt = 0; nt < 4; nt++) {
      acc[nt][0] = bf2f(egv[nt].x); acc[nt][1] = bf2f(egv[nt].y);
      acc[nt][2] = bf2f(egv[nt].z); acc[nt][3] = bf2f(egv[nt].w);
    }

    if (t > 0) {
      // Throttle: wait until all 32 producer waves of this half signalled
      // step t-1 (flag >= t). Lanes with a cached satisfied flag issue no
      // loads; only straggler lines are re-polled.
      bool ready = (lane >= 32) | (fcache >= (unsigned)t);
      while (!__all(ready)) {
        if (!ready) { fcache = allc32(pollp); ready = (fcache >= (unsigned)t); }
      }
      asm volatile("" ::: "memory");   // no compiler motion of h loads above

      // Bulk h(t-1) loads: NORMAL CACHED, coalesced (16 consecutive-b lanes
      // share one contiguous 128B line). First touch of these addresses by
      // this WG -> L2 miss -> fresh from LLC in the common case.
      const unsigned long long* hp = hist + (size_t)(t - 1) * 4096 + b;
      unsigned long long v[32];
      #pragma unroll
      for (int kc = 0; kc < 16; kc++) {
        v[2 * kc]     = hp[(kc * 8 + q * 2    ) * 32];
        v[2 * kc + 1] = hp[(kc * 8 + q * 2 + 1) * 32];
      }

      #pragma unroll
      for (int kc = 0; kc < 16; kc++) {
        // Validate this K-chunk; only stragglers take the atomic re-poll path
        // (bypasses any stale poison copy in L1/XCD-L2; slots are write-once,
        // SENT -> data, never back, so redundant reloads are harmless).
        while (__any((v[2 * kc] == SENT) | (v[2 * kc + 1] == SENT))) {
          v[2 * kc]     = allc64(hp + (kc * 8 + q * 2    ) * 32);
          v[2 * kc + 1] = allc64(hp + (kc * 8 + q * 2 + 1) * 32);
        }
        BF8 hf; hf.q[0] = v[2 * kc]; hf.q[1] = v[2 * kc + 1];
        #pragma unroll
        for (int nt = 0; nt < 4; nt++) {
          BF8 af; af.v = wlds[((nt * 16 + kc) << 6) + (nl << 2) + q];
          acc[nt] = __builtin_amdgcn_mfma_f32_16x16x32_bf16(af.b, hf.b, acc[nt], 0, 0, 0);
        }
      }
    }

    float4 ov;
    BF4 hb;
    {
      float i0 = sigm(acc[0][0]), f0 = sigm(acc[1][0]), g0v = tanh_(acc[2][0]), o0 = sigm(acc[3][0]);
      float i1 = sigm(acc[0][1]), f1 = sigm(acc[1][1]), g1v = tanh_(acc[2][1]), o1 = sigm(acc[3][1]);
      float i2 = sigm(acc[0][2]), f2 = sigm(acc[1][2]), g2v = tanh_(acc[2][2]), o2 = sigm(acc[3][2]);
      float i3 = sigm(acc[0][3]), f3 = sigm(acc[1][3]), g3v = tanh_(acc[2][3]), o3 = sigm(acc[3][3]);
      ov.x = o0 * tanh_(f0 * c0r[0] + i0 * g0v);   // cell NOT carried: always c0
      ov.y = o1 * tanh_(f1 * c0r[1] + i1 * g1v);
      ov.z = o2 * tanh_(f2 * c0r[2] + i2 * g2v);
      ov.w = o3 * tanh_(f3 * c0r[3] + i3 * g3v);
      hb.u[0] = f2bf(ov.x); hb.u[1] = f2bf(ov.y); hb.u[2] = f2bf(ov.z); hb.u[3] = f2bf(ov.w);
    }
    // h slot t: ONE coalesced u64 atomic store per lane (16 lanes -> 128B).
    __hip_atomic_store(hist + (size_t)t * 4096 + (size_t)jblk * 32 + b,
                       hb.q, __ATOMIC_RELAXED, __HIP_MEMORY_SCOPE_AGENT);
    // Signal immediately: plain atomic STORE (no RMW, no drain). Sentinel
    // validation covers the signal-beats-data race.
    if (lane == 0)
      __hip_atomic_store(myflag, (unsigned)(t + 1),
                         __ATOMIC_RELAXED, __HIP_MEMORY_SCOPE_AGENT);
    // out[b][t][jq..jq+3] — cached store, fully off the signalling path
    *(float4*)(out + (size_t)b * (SLEN * HDIM) + (size_t)t * HDIM + jq) = ov;

    #pragma unroll
    for (int nt = 0; nt < 4; nt++) egv[nt] = egp[nt];
  }
}

// ---------------------------------------------------------------------------
// Workspace (~80.3 MiB):
//   [0,       262144)    const[g][b] f32
//   [262144,  264192)    64 flag words (32B stride, 2KB), zeroed by k_const
//   [264192, +64 MiB)    eg[s][b][g] bf16 (const baked in)
//   [67373056, +16 MiB)  h history: 512 slots x 4096 u64 (j-major [j/4][b]),
//                        poisoned to 0xFF each launch (sentinel protocol)
// ---------------------------------------------------------------------------
extern "C" void kernel_launch(void* const* d_in, const int* in_sizes, int n_in,
                              void* d_out, int out_size, void* d_ws, size_t ws_size,
                              hipStream_t stream)
{
  (void)in_sizes; (void)n_in; (void)out_size; (void)ws_size;
  const int*   seq  = (const int*)d_in[0];
  // d_in[1] = enc_out : unused by the reference math
  const float* ench = (const float*)d_in[2];
  const float* encc = (const float*)d_in[3];
  const float* emb  = (const float*)d_in[4];
  const float* Wih  = (const float*)d_in[5];
  const float* Whh  = (const float*)d_in[6];
  const float* bih  = (const float*)d_in[7];
  const float* bhh  = (const float*)d_in[8];
  float* out = (float*)d_out;

  char* ws = (char*)d_ws;
  float*    cgb   = (float*)ws;
  unsigned* flags = (unsigned*)(ws + 262144);
  uint16_t* eg    = (uint16_t*)(ws + 264192);
  unsigned long long* hist = (unsigned long long*)(ws + 67373056);

  // Poison hist to the sentinel (stream-ordered: previous replay's k_scan has
  // fully retired; k_scan below sees only poisoned lines until produced).
  hipMemsetAsync(hist, 0xFF, (size_t)SLEN * 4096 * 8, stream);
  k_const<<<dim3(256),  dim3(256), 0, stream>>>(Whh, ench, bih, bhh, cgb, flags);
  k_emb  <<<dim3(4096), dim3(256), 0, stream>>>(seq, emb, Wih, cgb, eg);
  k_scan <<<dim3(GWG),  dim3(128), 0, stream>>>(Wih, encc, eg, hist, out, flags);
}

// Round 4
// 1962.120 us; speedup vs baseline: 1.2311x; 1.2311x over previous
//
#include <hip/hip_runtime.h>
#include <stdint.h>

// Problem constants (DecoderLSTM): VOCAB=50257, E=H=512, B=32, S=512
// ALL float tensors are fp32; sequence is int32. Internal bf16 MFMA; fp32 out.
#define EDIM  512
#define HDIM  512
#define BSZ   32
#define SLEN  512
#define GDIM  2048   // 4*H
#define TEAMS 2      // independent batch-half recurrences
#define TWG   32     // scan workgroups per team (j-column split)

// Sentinel for unwritten hist u64s: 4x bf16 0xFFFF (-NaN). h = o*tanh(c) is in
// [-1,1]; f2bf of any finite in-range value can never produce 0xFFFF, and the
// u64 store is atomic (no tearing), so "u64 != SENT" == "data ready".
#define SENT 0xFFFFFFFFFFFFFFFFull

typedef __bf16 bf16x8 __attribute__((ext_vector_type(8)));
typedef float  f32x4  __attribute__((ext_vector_type(4)));

__device__ __forceinline__ uint16_t f2bf(float f) {
  union { float f; uint32_t i; } v; v.f = f;
  uint32_t r = v.i + 0x7FFFu + ((v.i >> 16) & 1u);  // RNE
  return (uint16_t)(r >> 16);
}
__device__ __forceinline__ float bf2f(uint32_t u) {
  union { uint32_t i; float f; } v; v.i = u << 16; return v.f;
}
union BF8 { uint16_t u[8]; uint4 v; bf16x8 b; unsigned long long q[2]; };
union BF4 { uint16_t u[4]; unsigned long long q; };
__device__ __forceinline__ uint4 pack8(float4 lo, float4 hi) {
  BF8 r;
  r.u[0] = f2bf(lo.x); r.u[1] = f2bf(lo.y); r.u[2] = f2bf(lo.z); r.u[3] = f2bf(lo.w);
  r.u[4] = f2bf(hi.x); r.u[5] = f2bf(hi.y); r.u[6] = f2bf(hi.z); r.u[7] = f2bf(hi.w);
  return r.v;
}
__device__ __forceinline__ float sigm(float x) { return 1.0f / (1.0f + __expf(-x)); }
__device__ __forceinline__ float tanh_(float x) {
  float ax = fabsf(x);
  float e  = __expf(2.0f * ax);          // overflow-safe: e=inf -> t=1
  float t  = 1.0f - 2.0f / (e + 1.0f);
  return copysignf(t, x);
}
// Atomic (LLC, L1/L2-bypassing) u64 load — straggler re-poll path only.
__device__ __forceinline__ unsigned long long allc64(const unsigned long long* p) {
  return __hip_atomic_load(p, __ATOMIC_RELAXED, __HIP_MEMORY_SCOPE_AGENT);
}

// ---------------------------------------------------------------------------
// K1: const[g][b] = sum_k W_hh[g][k]*h0[b][k] + b_ih[g] + b_hh[g] (fp32)
// ---------------------------------------------------------------------------
__global__ __launch_bounds__(256) void k_const(
    const float* __restrict__ Whh, const float* __restrict__ h0,
    const float* __restrict__ bih, const float* __restrict__ bhh,
    float* __restrict__ cgb)
{
  int idx = blockIdx.x * 256 + threadIdx.x;        // 2048*32 = 65536
  int g = idx >> 5, b = idx & 31;
  const float4* w4 = (const float4*)(Whh + (size_t)g * HDIM);
  const float4* h4 = (const float4*)(h0  + (size_t)b * HDIM);
  float acc = 0.f;
  #pragma unroll 8
  for (int k = 0; k < HDIM / 4; k++) {
    float4 a = w4[k], c = h4[k];
    acc += a.x * c.x + a.y * c.y + a.z * c.z + a.w * c.w;
  }
  acc += bih[g] + bhh[g];
  cgb[idx] = acc;   // layout [g][b]
}

// ---------------------------------------------------------------------------
// K2: eg[s][b][g] (bf16) = sum_e emb[seq[b][s]][e] * W_ih[g][e] + const[g][b]
// (unchanged)
// ---------------------------------------------------------------------------
__global__ __launch_bounds__(256) void k_emb(
    const int* __restrict__ seq, const float* __restrict__ emb,
    const float* __restrict__ Wih, const float* __restrict__ cgb,
    uint16_t* __restrict__ eg)
{
  __shared__ uint4 wlds[4096];   // 64KB bf16, frag-order: [T=n>>4][kc][nl=n&15][q]
  const int tid = threadIdx.x;
  const int gc  = blockIdx.x & 31;   // 32 g-chunks of 64 rows
  const int sc  = blockIdx.x >> 5;   // 128 s-chunks of 4
  const int g0  = gc * 64, s0 = sc * 4;

  for (int i = tid; i < 64 * 64; i += 256) {       // 64 rows x 64 8-elem chunks
    int n = i >> 6, c = i & 63;
    const float* wp = Wih + (size_t)(g0 + n) * 1024 + c * 8;   // W_e = W_ih[:, :512]
    float4 lo = *(const float4*)(wp);
    float4 hi = *(const float4*)(wp + 4);
    wlds[(((n >> 4) * 16 + (c >> 2)) << 6) + ((n & 15) << 2) + (c & 3)] = pack8(lo, hi);
  }
  __syncthreads();

  const int lane = tid & 63, w = tid >> 6;
  const int q = lane >> 4, nl = lane & 15;
  const int Nt  = w & 1;            // b-tile
  const int Mt0 = (w >> 1) * 2;     // g-tile pair {Mt0, Mt0+1}
  const int bcol = Nt * 16 + nl;

  float c0i[4], c1i[4];             // baked const, fixed across s
  #pragma unroll
  for (int r = 0; r < 4; r++) {
    c0i[r] = cgb[(g0 + (Mt0    ) * 16 + q * 4 + r) * 32 + bcol];
    c1i[r] = cgb[(g0 + (Mt0 + 1) * 16 + q * 4 + r) * 32 + bcol];
  }

  for (int si = 0; si < 4; si++) {
    int s = s0 + si;
    int rowi = seq[bcol * SLEN + s];                 // gather index for this lane's b
    const float* brow = emb + (size_t)rowi * EDIM + q * 8;
    f32x4 acc0, acc1;
    #pragma unroll
    for (int r = 0; r < 4; r++) { acc0[r] = c0i[r]; acc1[r] = c1i[r]; }
    #pragma unroll 4
    for (int kc = 0; kc < 16; kc++) {
      float4 blo = *(const float4*)(brow + kc * 32);
      float4 bhi = *(const float4*)(brow + kc * 32 + 4);
      BF8 bf; bf.v = pack8(blo, bhi);
      BF8 a0; a0.v = wlds[(((Mt0    ) * 16 + kc) << 6) + (nl << 2) + q];
      BF8 a1; a1.v = wlds[(((Mt0 + 1) * 16 + kc) << 6) + (nl << 2) + q];
      acc0 = __builtin_amdgcn_mfma_f32_16x16x32_bf16(a0.b, bf.b, acc0, 0, 0, 0);
      acc1 = __builtin_amdgcn_mfma_f32_16x16x32_bf16(a1.b, bf.b, acc1, 0, 0, 0);
    }
    #pragma unroll
    for (int r = 0; r < 4; r++) {
      int m0 = (Mt0    ) * 16 + q * 4 + r;
      int m1 = (Mt0 + 1) * 16 + q * 4 + r;
      eg[((size_t)s * 32 + bcol) * GDIM + g0 + m0] = f2bf(acc0[r]);   // [s][b][g]
      eg[((size_t)s * 32 + bcol) * GDIM + g0 + m1] = f2bf(acc1[r]);
    }
  }
}

// ---------------------------------------------------------------------------
// K3: sequential scan — R11 "XCD-team" redesign.
// Post-mortem R9/R10: ~8.8k cy/step, invariant under signal-scheme changes ->
// the floor is 3-4 serial CROSS-XCD LLC round trips (~600-900cy each) + skew.
// The per-step exchange is only 16KB per batch-half: it fits in one XCD's L2
// (4MiB, coherent across its 32 CUs, ~200cy).
// R11: the two INDEPENDENT batch-half recurrences become 2 teams of 32
// single-wave WGs. team = blockIdx&7, wg = blockIdx>>3: under the observed
// round-robin bid%8->XCD dispatch, team 0 occupies XCD0 and team 1 XCD1, so
// all exchange traffic stays inside one L2.
//  * producer: plain u64 store (-> local XCD L2, write-through L1) PLUS an
//    agent-scope atomic store of the same value (LLC backstop).
//  * consumer: NO FLAGS. First pass = plain coalesced loads (L1 guaranteed
//    miss: addresses are step-unique; hits local L2 fresh when same-XCD).
//    Sentinel-validate all 32 u64s; if any poison, full re-poll passes via
//    agent-scope atomic loads (LLC, where the backstop lives, pipelined
//    across all 32 -> one ~700cy round per pass, not per chunk).
// Correctness is placement-INDEPENDENT (write-once slots + unreachable
// poison + LLC backstop => every spin terminates); placement only sets speed.
// ---------------------------------------------------------------------------
__global__ __launch_bounds__(64) void k_scan(
    const float* __restrict__ Wih, const float* __restrict__ c0,
    const uint16_t* __restrict__ eg, unsigned long long* __restrict__ hist,
    float* __restrict__ out)
{
  const int bid  = blockIdx.x;
  const int team = bid & 7;          // XCD id under round-robin dispatch
  if (team >= TEAMS) return;         // 192 of 256 WGs exit immediately
  const int wg   = bid >> 3;         // 0..31: j-slice within team

  __shared__ uint4 wlds[4096];   // 64KB: W_h slice, frag-order
  const int tid = threadIdx.x;   // 64 threads = 1 wave
  const int j0  = wg * 16;

  // Stage W_h slice: row n: gate=n>>4, jj=n&15 -> W_ih row gate*512+j0+jj, cols [512,1024)
  for (int i = tid; i < 64 * 64; i += 64) {
    int n = i >> 6, c = i & 63;
    int grow = (n >> 4) * HDIM + j0 + (n & 15);
    const float* wp = Wih + (size_t)grow * 1024 + 512 + c * 8;
    float4 lo = *(const float4*)(wp);
    float4 hi = *(const float4*)(wp + 4);
    wlds[(((n >> 4) * 16 + (c >> 2)) << 6) + ((n & 15) << 2) + (c & 3)] = pack8(lo, hi);
  }

  const int lane = tid;
  const int q = lane >> 4, nl = lane & 15;
  const int b  = team * 16 + nl;             // owned batch column (global)
  const int jq = j0 + q * 4;                 // owned j's: jq..jq+3
  const int jblk = wg * 4 + q;               // owned j-block within team (0..127)
  unsigned long long* ht = hist + (size_t)team * SLEN * 2048;  // team hist
  float c0r[4];
  #pragma unroll
  for (int r = 0; r < 4; r++) c0r[r] = c0[(size_t)b * HDIM + jq + r];
  __syncthreads();   // LDS W_h ready — the ONLY barrier in this kernel

  // Preload eg for t=0
  ushort4 egv[4], egp[4];
  #pragma unroll
  for (int nt = 0; nt < 4; nt++)
    egv[nt] = *(const ushort4*)(eg + ((size_t)0 * 32 + b) * GDIM + nt * HDIM + jq);

  for (int t = 0; t < SLEN; t++) {
    // Prefetch eg[t+1]: in flight across the entire step
    const int tn = (t + 1 < SLEN) ? t + 1 : t;
    #pragma unroll
    for (int nt = 0; nt < 4; nt++)
      egp[nt] = *(const ushort4*)(eg + ((size_t)tn * 32 + b) * GDIM + nt * HDIM + jq);

    f32x4 acc[4];
    #pragma unroll
    for (int nt = 0; nt < 4; nt++) {
      acc[nt][0] = bf2f(egv[nt].x); acc[nt][1] = bf2f(egv[nt].y);
      acc[nt][2] = bf2f(egv[nt].z); acc[nt][3] = bf2f(egv[nt].w);
    }

    if (t > 0) {
      // Pass 1: plain coalesced loads of h(t-1). Per (kc,dd) instruction the
      // wave touches 4 distinct 128B lines (one per q-group) -> 4 txns.
      // L1 misses by construction (step-unique addresses); same-XCD -> L2 hit
      // on the producer's plain store.
      const unsigned long long* hp = ht + (size_t)(t - 1) * 2048 + nl;
      unsigned long long v[32];
      #pragma unroll
      for (int kc = 0; kc < 16; kc++) {
        v[2 * kc]     = hp[(kc * 8 + q * 2    ) * 16];
        v[2 * kc + 1] = hp[(kc * 8 + q * 2 + 1) * 16];
      }
      // Sentinel validation; full-pass atomic re-poll for stragglers
      // (pipelined: ~one LLC round trip per pass, regardless of chunk count).
      bool any = false;
      #pragma unroll
      for (int i = 0; i < 32; i++) any |= (v[i] == SENT);
      while (__any(any)) {
        #pragma unroll
        for (int kc = 0; kc < 16; kc++) {
          v[2 * kc]     = allc64(hp + (kc * 8 + q * 2    ) * 16);
          v[2 * kc + 1] = allc64(hp + (kc * 8 + q * 2 + 1) * 16);
        }
        any = false;
        #pragma unroll
        for (int i = 0; i < 32; i++) any |= (v[i] == SENT);
      }

      #pragma unroll
      for (int kc = 0; kc < 16; kc++) {
        BF8 hf; hf.q[0] = v[2 * kc]; hf.q[1] = v[2 * kc + 1];
        #pragma unroll
        for (int nt = 0; nt < 4; nt++) {
          BF8 af; af.v = wlds[((nt * 16 + kc) << 6) + (nl << 2) + q];
          acc[nt] = __builtin_amdgcn_mfma_f32_16x16x32_bf16(af.b, hf.b, acc[nt], 0, 0, 0);
        }
      }
    }

    float4 ov;
    BF4 hb;
    {
      float i0 = sigm(acc[0][0]), f0 = sigm(acc[1][0]), g0v = tanh_(acc[2][0]), o0 = sigm(acc[3][0]);
      float i1 = sigm(acc[0][1]), f1 = sigm(acc[1][1]), g1v = tanh_(acc[2][1]), o1 = sigm(acc[3][1]);
      float i2 = sigm(acc[0][2]), f2 = sigm(acc[1][2]), g2v = tanh_(acc[2][2]), o2 = sigm(acc[3][2]);
      float i3 = sigm(acc[0][3]), f3 = sigm(acc[1][3]), g3v = tanh_(acc[2][3]), o3 = sigm(acc[3][3]);
      ov.x = o0 * tanh_(f0 * c0r[0] + i0 * g0v);   // cell NOT carried: always c0
      ov.y = o1 * tanh_(f1 * c0r[1] + i1 * g1v);
      ov.z = o2 * tanh_(f2 * c0r[2] + i2 * g2v);
      ov.w = o3 * tanh_(f3 * c0r[3] + i3 * g3v);
      hb.u[0] = f2bf(ov.x); hb.u[1] = f2bf(ov.y); hb.u[2] = f2bf(ov.z); hb.u[3] = f2bf(ov.w);
    }
    // h slot t: plain store (-> local XCD L2, 16 nl-lanes = one 128B line)
    // + agent-scope atomic store of the SAME value (LLC backstop). Write-once
    // address, identical values -> any ordering/interleaving is consistent.
    unsigned long long* dst = ht + (size_t)t * 2048 + (size_t)jblk * 16 + nl;
    *dst = hb.q;
    __hip_atomic_store(dst, hb.q, __ATOMIC_RELAXED, __HIP_MEMORY_SCOPE_AGENT);
    // out[b][t][jq..jq+3] — cached store, off the signalling path
    *(float4*)(out + (size_t)b * (SLEN * HDIM) + (size_t)t * HDIM + jq) = ov;

    #pragma unroll
    for (int nt = 0; nt < 4; nt++) egv[nt] = egp[nt];
  }
}

// ---------------------------------------------------------------------------
// Workspace (~80.3 MiB):
//   [0,       262144)    const[g][b] f32
//   [262144,  264192)    (unused)
//   [264192, +64 MiB)    eg[s][b][g] bf16 (const baked in)
//   [67373056, +16 MiB)  h history: 2 teams x 512 slots x 2048 u64
//                        ([jblk(128)][b(16)] per slot), poisoned to 0xFF
//                        each launch (sentinel protocol)
// ---------------------------------------------------------------------------
extern "C" void kernel_launch(void* const* d_in, const int* in_sizes, int n_in,
                              void* d_out, int out_size, void* d_ws, size_t ws_size,
                              hipStream_t stream)
{
  (void)in_sizes; (void)n_in; (void)out_size; (void)ws_size;
  const int*   seq  = (const int*)d_in[0];
  // d_in[1] = enc_out : unused by the reference math
  const float* ench = (const float*)d_in[2];
  const float* encc = (const float*)d_in[3];
  const float* emb  = (const float*)d_in[4];
  const float* Wih  = (const float*)d_in[5];
  const float* Whh  = (const float*)d_in[6];
  const float* bih  = (const float*)d_in[7];
  const float* bhh  = (const float*)d_in[8];
  float* out = (float*)d_out;

  char* ws = (char*)d_ws;
  float*    cgb   = (float*)ws;
  uint16_t* eg    = (uint16_t*)(ws + 264192);
  unsigned long long* hist = (unsigned long long*)(ws + 67373056);

  // Poison hist to the sentinel (stream-ordered: previous replay's k_scan has
  // fully retired; k_scan below sees only poisoned lines until produced).
  hipMemsetAsync(hist, 0xFF, (size_t)TEAMS * SLEN * 2048 * 8, stream);
  k_const<<<dim3(256),  dim3(256), 0, stream>>>(Whh, ench, bih, bhh, cgb);
  k_emb  <<<dim3(4096), dim3(256), 0, stream>>>(seq, emb, Wih, cgb, eg);
  // 256 WGs: bid&7 selects the XCD under round-robin dispatch; teams 0/1
  // participate (32 WGs each, XCD-pure if the heuristic holds), rest exit.
  k_scan <<<dim3(256),  dim3(64),  0, stream>>>(Wih, encc, eg, hist, out);
}